// Round 3
// baseline (3520.718 us; speedup 1.0000x reference)
//
#include <hip/hip_runtime.h>
#include <hip/hip_bf16.h>

typedef __hip_bfloat16 bf16;

static __device__ __forceinline__ float tf(const bf16 v) { return __bfloat162float(v); }

// load from an input buffer whose dtype is decided at runtime (f32 flag)
static __device__ __forceinline__ float ldv(const void* p, size_t i, bool f32) {
    return f32 ? ((const float*)p)[i] : tf(((const bf16*)p)[i]);
}

constexpr int Bz = 16, Lz = 1024, DM = 512, DI = 1024, ST = 16, DC = 4, RK = 32, OD = 128;
constexpr int Mrows = Bz * Lz;           // 16384
constexpr int XD = RK + 2 * ST;          // 64 (x_dbl row)

// -------- dtype probe: sample even bf16 halves of x; f32 data -> wild values --------
__global__ void detect_kernel(const void* __restrict__ xp, int* __restrict__ flag) {
    int i = blockIdx.x * 256 + threadIdx.x;          // 0..65535
    const bf16* p = (const bf16*)xp;
    float v = tf(p[(size_t)i * 64]);                 // even idx = low half if f32
    if (!(fabsf(v) < 1e4f)) atomicAdd(flag, 1);      // NaN/inf/huge counts
}

// ---------------- 64x64 tiled GEMM, fp32 accumulate ----------------
// C[M,N] = A[M,K] @ B[K, bcol:bcol+N], strides lda/ldb/ldc. AIN/BIN: input buffers
// (runtime dtype). CF32: write fp32 else bf16.
template <bool AIN, bool BIN, bool CF32>
__global__ __launch_bounds__(256) void gemm64(const void* __restrict__ A, int lda,
                                              const void* __restrict__ B, int ldb, int bcol,
                                              void* __restrict__ C, int ldc,
                                              int M, int N, int K,
                                              const int* __restrict__ flag) {
    const bool f32m = (*flag != 0);
    const bool fA = AIN && f32m;
    const bool fB = BIN && f32m;
    __shared__ float As[16][68];
    __shared__ float Bs[16][68];
    const int tid = threadIdx.x;
    const int tx = tid & 15;        // n-dir
    const int ty = tid >> 4;        // m-dir
    const int m0 = blockIdx.y * 64;
    const int n0 = blockIdx.x * 64;
    float acc[4][4] = {};
    for (int k0 = 0; k0 < K; k0 += 16) {
        #pragma unroll
        for (int q = 0; q < 4; ++q) {
            int idx = tid + q * 256;
            int kk = idx & 15, m = idx >> 4;          // A: 64x16
            As[kk][m] = ldv(A, (size_t)(m0 + m) * lda + k0 + kk, fA);
            int n = idx & 63, kb = idx >> 6;          // B: 16x64
            Bs[kb][n] = ldv(B, (size_t)(k0 + kb) * ldb + bcol + n0 + n, fB);
        }
        __syncthreads();
        #pragma unroll
        for (int kk = 0; kk < 16; ++kk) {
            float a[4], bv[4];
            #pragma unroll
            for (int i = 0; i < 4; ++i) a[i] = As[kk][ty * 4 + i];
            #pragma unroll
            for (int j = 0; j < 4; ++j) bv[j] = Bs[kk][tx * 4 + j];
            #pragma unroll
            for (int i = 0; i < 4; ++i)
                #pragma unroll
                for (int j = 0; j < 4; ++j) acc[i][j] += a[i] * bv[j];
        }
        __syncthreads();
    }
    #pragma unroll
    for (int i = 0; i < 4; ++i)
        #pragma unroll
        for (int j = 0; j < 4; ++j) {
            size_t ci = (size_t)(m0 + ty * 4 + i) * ldc + n0 + tx * 4 + j;
            if (CF32) ((float*)C)[ci] = acc[i][j];
            else      ((bf16*)C)[ci]  = __float2bfloat16(acc[i][j]);
        }
}

// ---------------- conv (depthwise, causal, DC=4) + SiLU ----------------
__global__ __launch_bounds__(256) void conv_silu_kernel(const bf16* __restrict__ xin,
                                                        const void* __restrict__ conv_w,
                                                        const void* __restrict__ conv_b,
                                                        bf16* __restrict__ xc,
                                                        const int* __restrict__ flag) {
    const bool f = (*flag != 0);
    int g = blockIdx.x * 256 + threadIdx.x;       // g = b*2^20 + t*2^10 + d
    int d = g & (DI - 1);
    int t = (g >> 10) & (Lz - 1);
    int b = g >> 20;
    const bf16* xin_b = xin + (size_t)b * Lz * DI;
    float acc = ldv(conv_b, d, f);
    #pragma unroll
    for (int j = 0; j < DC; ++j) {
        int tt = t + j - (DC - 1);
        if (tt >= 0) acc += tf(xin_b[(size_t)tt * DI + d]) * ldv(conv_w, d * DC + j, f);
    }
    xc[(size_t)g] = __float2bfloat16(acc / (1.f + __expf(-acc)));
}

// -------- selective scan (dt-GEMM fused): 16 lanes per (b,d) channel --------
__global__ __launch_bounds__(256) void scan_kernel(const float* __restrict__ x_dbl,
                                                   const bf16* __restrict__ z,
                                                   const bf16* __restrict__ xc,
                                                   const void* __restrict__ W_dt,
                                                   const void* __restrict__ b_dt,
                                                   const void* __restrict__ A_log,
                                                   const void* __restrict__ Dp,
                                                   bf16* __restrict__ y,
                                                   const int* __restrict__ flag) {
    const bool f = (*flag != 0);
    int g = blockIdx.x * 256 + threadIdx.x;    // g = b*2^14 + d*2^4 + s
    int s = g & 15;
    int d = (g >> 4) & (DI - 1);
    int b = g >> 14;
    // per-lane slice of W_dt column d (K=32, 2 per lane)
    float w0 = ldv(W_dt, (size_t)(2 * s) * DI + d, f);
    float w1 = ldv(W_dt, (size_t)(2 * s + 1) * DI + d, f);
    float bd = ldv(b_dt, d, f);
    float A_s = -__expf(ldv(A_log, d * ST + s, f));
    float Dp_d = ldv(Dp, d, f);
    float h = 0.f;
    const float* xd  = x_dbl + (size_t)b * Lz * XD;
    const bf16* xc_b = xc + (size_t)b * Lz * DI + d;
    const bf16* z_b  = z  + (size_t)b * Lz * DI + d;
    bf16* y_b        = y  + (size_t)b * Lz * DI + d;
    for (int t = 0; t < Lz; ++t) {
        const float* xr = xd + (size_t)t * XD;
        // dt = softplus(x_dbl[t,:32] . W_dt[:,d] + b_dt[d]) — butterfly all-reduce
        float part = xr[2 * s] * w0 + xr[2 * s + 1] * w1;
        part += __shfl_xor(part, 1, 16);
        part += __shfl_xor(part, 2, 16);
        part += __shfl_xor(part, 4, 16);
        part += __shfl_xor(part, 8, 16);
        float a = part + bd;
        float dtv = (a > 20.f) ? a : log1pf(__expf(a));
        float u  = tf(xc_b[(size_t)t * DI]);
        float Bv = xr[RK + s];
        float Cv = xr[RK + ST + s];
        h = h * __expf(dtv * A_s) + dtv * u * Bv;
        float p = h * Cv;
        p += __shfl_xor(p, 1, 16);
        p += __shfl_xor(p, 2, 16);
        p += __shfl_xor(p, 4, 16);
        p += __shfl_xor(p, 8, 16);
        if (s == 0) {
            float zz = tf(z_b[(size_t)t * DI]);
            float yv = (p + Dp_d * u) * (zz / (1.f + __expf(-zz)));
            y_b[(size_t)t * DI] = __float2bfloat16(yv);
        }
    }
}

// ---------------- final FC stage 1: partial dot over k-chunks ----------------
__global__ __launch_bounds__(128) void fc_partial_kernel(const bf16* __restrict__ out_pre,
                                                         const void* __restrict__ W_fc,
                                                         float* __restrict__ accbuf,
                                                         const int* __restrict__ flag) {
    const bool f = (*flag != 0);
    const int n = threadIdx.x;                   // 0..127
    const int KC = (Lz * DM) / 512;              // 1024
    const int k0 = blockIdx.x * KC;
    float acc[Bz];
    #pragma unroll
    for (int b = 0; b < Bz; ++b) acc[b] = 0.f;
    for (int k = k0; k < k0 + KC; ++k) {
        float w = ldv(W_fc, (size_t)k * OD + n, f);
        #pragma unroll
        for (int b = 0; b < Bz; ++b) acc[b] += tf(out_pre[(size_t)b * (Lz * DM) + k]) * w;
    }
    #pragma unroll
    for (int b = 0; b < Bz; ++b) atomicAdd(&accbuf[b * OD + n], acc[b]);
}

__global__ void fc_final_kernel(const float* __restrict__ accbuf,
                                const void* __restrict__ b_fc, void* __restrict__ out,
                                const int* __restrict__ flag) {
    const bool f = (*flag != 0);
    int i = blockIdx.x * 256 + threadIdx.x;
    if (i < Bz * OD) {
        float v = accbuf[i] + ldv(b_fc, i & (OD - 1), f);
        if (f) ((float*)out)[i] = v;
        else   ((bf16*)out)[i]  = __float2bfloat16(v);
    }
}

extern "C" void kernel_launch(void* const* d_in, const int* in_sizes, int n_in,
                              void* d_out, int out_size, void* d_ws, size_t ws_size,
                              hipStream_t stream) {
    const void* x       = d_in[0];
    const void* W_in    = d_in[1];
    const void* conv_w  = d_in[2];
    const void* conv_b  = d_in[3];
    const void* W_xproj = d_in[4];
    const void* W_dt    = d_in[5];
    const void* b_dt    = d_in[6];
    const void* A_log   = d_in[7];
    const void* Dp      = d_in[8];
    const void* W_out   = d_in[9];
    const void* W_fc    = d_in[10];
    const void* b_fc    = d_in[11];

    // workspace layout (bytes), total ~100.01 MB, with aliasing:
    char* ws = (char*)d_ws;
    bf16*  xin   = (bf16*)(ws);                          // [0,32M)   16384x1024 bf16
    bf16*  z     = (bf16*)(ws + 33554432ull);            // [32M,64M)
    bf16*  xc    = (bf16*)(ws + 67108864ull);            // [64M,96M)
    float* x_dbl = (float*)(ws + 100663296ull);          // [96M,100M) 16384x64 fp32
    bf16*  y     = (bf16*)(ws);                          // alias xin (dead after conv)
    bf16*  outp  = (bf16*)(ws + 33554432ull);            // alias z   (dead after scan)
    float* accb  = (float*)(ws + 104857600ull);          // [100M, +8KB)
    int*   flag  = (int*)(ws + 104865792ull);            // +4

    dim3 blk(256);
    hipMemsetAsync(flag, 0, 4, stream);
    detect_kernel<<<256, blk, 0, stream>>>(x, flag);
    // K1: xin = x @ W_in[:, :DI] ; z = x @ W_in[:, DI:]
    hipLaunchKernelGGL((gemm64<true, true, false>), dim3(DI / 64, Mrows / 64), blk, 0, stream,
                       x, DM, W_in, 2 * DI, 0, xin, DI, Mrows, DI, DM, flag);
    hipLaunchKernelGGL((gemm64<true, true, false>), dim3(DI / 64, Mrows / 64), blk, 0, stream,
                       x, DM, W_in, 2 * DI, DI, z, DI, Mrows, DI, DM, flag);
    // K2: xc = silu(conv(xin))
    conv_silu_kernel<<<(Mrows * DI) / 256, blk, 0, stream>>>(xin, conv_w, conv_b, xc, flag);
    // K3: x_dbl = xc @ W_xproj  (16384x1024 @ 1024x64)
    hipLaunchKernelGGL((gemm64<false, true, true>), dim3(XD / 64, Mrows / 64), blk, 0, stream,
                       xc, DI, W_xproj, XD, 0, x_dbl, XD, Mrows, XD, DI, flag);
    // K4: selective scan (dt fused) -> y (includes +Dp*xc and *silu(z))
    scan_kernel<<<(Bz * DI * ST) / 256, blk, 0, stream>>>(x_dbl, z, xc, W_dt, b_dt,
                                                          A_log, Dp, y, flag);
    // K5: outp = y @ W_out  (16384x1024 @ 1024x512)
    hipLaunchKernelGGL((gemm64<false, true, false>), dim3(DM / 64, Mrows / 64), blk, 0, stream,
                       y, DI, W_out, DM, 0, outp, DM, Mrows, DM, DI, flag);
    // K6: final FC (16 x 524288) @ (524288 x 128) + b_fc
    hipMemsetAsync(accb, 0, Bz * OD * sizeof(float), stream);
    fc_partial_kernel<<<512, dim3(128), 0, stream>>>(outp, W_fc, accb, flag);
    fc_final_kernel<<<(Bz * OD + 255) / 256, blk, 0, stream>>>(accb, b_fc, d_out, flag);
}

// Round 4
// 2081.296 us; speedup vs baseline: 1.6916x; 1.6916x over previous
//
#include <hip/hip_runtime.h>
#include <hip/hip_bf16.h>

typedef __hip_bfloat16 bf16;
typedef __bf16 bf8v __attribute__((ext_vector_type(8)));
typedef float f4v __attribute__((ext_vector_type(4)));

static __device__ __forceinline__ float tf(const bf16 v) { return __bfloat162float(v); }

// load from an input buffer whose dtype is decided at runtime (f32 flag)
static __device__ __forceinline__ float ldv(const void* p, size_t i, bool f32) {
    return f32 ? ((const float*)p)[i] : tf(((const bf16*)p)[i]);
}

constexpr int Bz = 16, Lz = 1024, DM = 512, DI = 1024, ST = 16, DC = 4, RK = 32, OD = 128;
constexpr int Mrows = Bz * Lz;           // 16384
constexpr int XD = RK + 2 * ST;          // 64 (x_dbl row)

// -------- dtype probe: sample even bf16 halves of x; f32 data -> wild values --------
__global__ void detect_kernel(const void* __restrict__ xp, int* __restrict__ flag) {
    int i = blockIdx.x * 256 + threadIdx.x;          // 0..65535
    const bf16* p = (const bf16*)xp;
    float v = tf(p[(size_t)i * 64]);                 // even idx = low half if f32
    if (!(fabsf(v) < 1e4f)) atomicAdd(flag, 1);      // NaN/inf/huge counts
}

// ================= MFMA bf16 GEMM: 128x128 tile, 4 waves, 16x16x32 =================
// C[M,N](bf16) = A[M,K] @ B[K, bcol:bcol+N]. AIN/BIN: runtime-dtype input buffers.
// ESILU: apply silu to result. Grid: (N/128, M/128). K % 32 == 0.
constexpr int APITCH = 40;    // shorts per A-lds row (128 rows)
constexpr int BPITCH = 140;   // shorts per B-lds row (32 rows)

template <bool AIN, bool BIN, bool ESILU>
__global__ __launch_bounds__(256) void gemm_mfma(const void* __restrict__ A, int lda,
                                                 const void* __restrict__ B, int ldb, int bcol,
                                                 bf16* __restrict__ C, int ldc, int K,
                                                 const int* __restrict__ flag) {
    const bool f32m = (*flag != 0);
    __shared__ __align__(16) __bf16 As[128 * APITCH];
    __shared__ __align__(16) __bf16 Bs[32 * BPITCH];
    const int tid = threadIdx.x;
    const int lane = tid & 63, wave = tid >> 6;
    const int wm = (wave >> 1) * 64, wn = (wave & 1) * 64;
    const int l15 = lane & 15, quad = lane >> 4;
    const int m0 = blockIdx.y * 128, n0 = blockIdx.x * 128;

    f4v acc[4][4];
    #pragma unroll
    for (int i = 0; i < 4; ++i)
        #pragma unroll
        for (int j = 0; j < 4; ++j)
            #pragma unroll
            for (int r = 0; r < 4; ++r) acc[i][j][r] = 0.f;

    const int am = tid >> 1, ak = (tid & 1) * 16;    // A: 128x32, 16 per thread
    const int bk = tid >> 3, bn = (tid & 7) * 16;    // B: 32x128, 16 per thread

    for (int k0 = 0; k0 < K; k0 += 32) {
        // ---- stage A tile (convert to bf16) ----
        if (AIN && f32m) {
            const float* Af = (const float*)A + (size_t)(m0 + am) * lda + k0 + ak;
            #pragma unroll
            for (int q = 0; q < 16; ++q) As[am * APITCH + ak + q] = (__bf16)Af[q];
        } else {
            const bf16* Ab = (const bf16*)A + (size_t)(m0 + am) * lda + k0 + ak;
            #pragma unroll
            for (int q = 0; q < 16; ++q) As[am * APITCH + ak + q] = (__bf16)tf(Ab[q]);
        }
        // ---- stage B tile ----
        if (BIN && f32m) {
            const float* Bf = (const float*)B + (size_t)(k0 + bk) * ldb + bcol + n0 + bn;
            #pragma unroll
            for (int q = 0; q < 16; ++q) Bs[bk * BPITCH + bn + q] = (__bf16)Bf[q];
        } else {
            const bf16* Bb = (const bf16*)B + (size_t)(k0 + bk) * ldb + bcol + n0 + bn;
            #pragma unroll
            for (int q = 0; q < 16; ++q) Bs[bk * BPITCH + bn + q] = (__bf16)tf(Bb[q]);
        }
        __syncthreads();
        // ---- fragments: A[m = lane&15][k = quad*8+j], B[k = quad*8+j][n = lane&15] ----
        bf8v a[4], b[4];
        #pragma unroll
        for (int mi = 0; mi < 4; ++mi)
            a[mi] = *(const bf8v*)&As[(wm + mi * 16 + l15) * APITCH + quad * 8];
        #pragma unroll
        for (int ni = 0; ni < 4; ++ni)
            #pragma unroll
            for (int j = 0; j < 8; ++j)
                b[ni][j] = Bs[(quad * 8 + j) * BPITCH + wn + ni * 16 + l15];
        #pragma unroll
        for (int mi = 0; mi < 4; ++mi)
            #pragma unroll
            for (int ni = 0; ni < 4; ++ni)
                acc[mi][ni] = __builtin_amdgcn_mfma_f32_16x16x32_bf16(a[mi], b[ni], acc[mi][ni], 0, 0, 0);
        __syncthreads();
    }
    // ---- epilogue: D row = quad*4 + r, col = lane&15 ----
    #pragma unroll
    for (int mi = 0; mi < 4; ++mi)
        #pragma unroll
        for (int ni = 0; ni < 4; ++ni)
            #pragma unroll
            for (int r = 0; r < 4; ++r) {
                int row = m0 + wm + mi * 16 + quad * 4 + r;
                int col = n0 + wn + ni * 16 + l15;
                float v = acc[mi][ni][r];
                if (ESILU) v = v / (1.f + __expf(-v));
                C[(size_t)row * ldc + col] = __float2bfloat16(v);
            }
}

// ---------------- 64x64 tiled vector GEMM (kept for K3: N=64, f32 out) ----------------
template <bool AIN, bool BIN, bool CF32>
__global__ __launch_bounds__(256) void gemm64(const void* __restrict__ A, int lda,
                                              const void* __restrict__ B, int ldb, int bcol,
                                              void* __restrict__ C, int ldc,
                                              int M, int N, int K,
                                              const int* __restrict__ flag) {
    const bool f32m = (*flag != 0);
    const bool fA = AIN && f32m;
    const bool fB = BIN && f32m;
    __shared__ float As[16][68];
    __shared__ float Bs[16][68];
    const int tid = threadIdx.x;
    const int tx = tid & 15;        // n-dir
    const int ty = tid >> 4;        // m-dir
    const int m0 = blockIdx.y * 64;
    const int n0 = blockIdx.x * 64;
    float acc[4][4] = {};
    for (int k0 = 0; k0 < K; k0 += 16) {
        #pragma unroll
        for (int q = 0; q < 4; ++q) {
            int idx = tid + q * 256;
            int kk = idx & 15, m = idx >> 4;          // A: 64x16
            As[kk][m] = ldv(A, (size_t)(m0 + m) * lda + k0 + kk, fA);
            int n = idx & 63, kb = idx >> 6;          // B: 16x64
            Bs[kb][n] = ldv(B, (size_t)(k0 + kb) * ldb + bcol + n0 + n, fB);
        }
        __syncthreads();
        #pragma unroll
        for (int kk = 0; kk < 16; ++kk) {
            float a[4], bv[4];
            #pragma unroll
            for (int i = 0; i < 4; ++i) a[i] = As[kk][ty * 4 + i];
            #pragma unroll
            for (int j = 0; j < 4; ++j) bv[j] = Bs[kk][tx * 4 + j];
            #pragma unroll
            for (int i = 0; i < 4; ++i)
                #pragma unroll
                for (int j = 0; j < 4; ++j) acc[i][j] += a[i] * bv[j];
        }
        __syncthreads();
    }
    #pragma unroll
    for (int i = 0; i < 4; ++i)
        #pragma unroll
        for (int j = 0; j < 4; ++j) {
            size_t ci = (size_t)(m0 + ty * 4 + i) * ldc + n0 + tx * 4 + j;
            if (CF32) ((float*)C)[ci] = acc[i][j];
            else      ((bf16*)C)[ci]  = __float2bfloat16(acc[i][j]);
        }
}

// ---------------- conv (depthwise, causal, DC=4) + SiLU ----------------
__global__ __launch_bounds__(256) void conv_silu_kernel(const bf16* __restrict__ xin,
                                                        const void* __restrict__ conv_w,
                                                        const void* __restrict__ conv_b,
                                                        bf16* __restrict__ xc,
                                                        const int* __restrict__ flag) {
    const bool f = (*flag != 0);
    int g = blockIdx.x * 256 + threadIdx.x;       // g = b*2^20 + t*2^10 + d
    int d = g & (DI - 1);
    int t = (g >> 10) & (Lz - 1);
    int b = g >> 20;
    const bf16* xin_b = xin + (size_t)b * Lz * DI;
    float acc = ldv(conv_b, d, f);
    #pragma unroll
    for (int j = 0; j < DC; ++j) {
        int tt = t + j - (DC - 1);
        if (tt >= 0) acc += tf(xin_b[(size_t)tt * DI + d]) * ldv(conv_w, d * DC + j, f);
    }
    xc[(size_t)g] = __float2bfloat16(acc / (1.f + __expf(-acc)));
}

// ------------- dt pass: dt[m,d] = softplus(x_dbl[m,:32] @ W_dt[:,d] + b_dt[d]) -------------
__global__ __launch_bounds__(256) void dt_kernel(const float* __restrict__ x_dbl,
                                                 const void* __restrict__ W_dt,
                                                 const void* __restrict__ b_dt,
                                                 _Float16* __restrict__ dt,
                                                 const int* __restrict__ flag) {
    const bool f = (*flag != 0);
    int g = blockIdx.x * 256 + threadIdx.x;       // g = m*1024 + d
    int d = g & (DI - 1);
    int m = g >> 10;
    float acc = ldv(b_dt, d, f);
    const float* xr = x_dbl + (size_t)m * XD;
    #pragma unroll
    for (int k = 0; k < RK; ++k) acc += xr[k] * ldv(W_dt, (size_t)k * DI + d, f);
    float dtv = (acc > 15.f) ? acc : __logf(1.f + __expf(acc));
    dt[(size_t)g] = (_Float16)dtv;
}

// -------- selective scan: 16 lanes per (b,d) channel, dt precomputed --------
__global__ __launch_bounds__(256) void scan_kernel(const float* __restrict__ x_dbl,
                                                   const _Float16* __restrict__ dt,
                                                   const bf16* __restrict__ xc,
                                                   const void* __restrict__ A_log,
                                                   const void* __restrict__ Dp,
                                                   bf16* __restrict__ yzs,   // in: silu(z), out: y
                                                   const int* __restrict__ flag) {
    const bool f = (*flag != 0);
    int g = blockIdx.x * 256 + threadIdx.x;    // g = b*2^14 + d*2^4 + s
    int s = g & 15;
    int d = (g >> 4) & (DI - 1);
    int b = g >> 14;
    float A_s = -__expf(ldv(A_log, d * ST + s, f));
    float Dp_d = ldv(Dp, d, f);
    float h = 0.f;
    const float*    xd   = x_dbl + (size_t)b * Lz * XD;
    const _Float16* dt_b = dt + (size_t)b * Lz * DI + d;
    const bf16*     xc_b = xc + (size_t)b * Lz * DI + d;
    bf16*           yz_b = yzs + (size_t)b * Lz * DI + d;
    #pragma unroll 2
    for (int t = 0; t < Lz; ++t) {
        const float* xr = xd + (size_t)t * XD;
        float dtv = (float)dt_b[(size_t)t * DI];
        float u   = tf(xc_b[(size_t)t * DI]);
        float Bv  = xr[RK + s];
        float Cv  = xr[RK + ST + s];
        h = h * __expf(dtv * A_s) + (dtv * u) * Bv;
        float p = h * Cv;
        p += __shfl_xor(p, 1, 16);
        p += __shfl_xor(p, 2, 16);
        p += __shfl_xor(p, 4, 16);
        p += __shfl_xor(p, 8, 16);
        if (s == 0) {
            float zz = tf(yz_b[(size_t)t * DI]);            // silu(z), precomputed
            yz_b[(size_t)t * DI] = __float2bfloat16((p + Dp_d * u) * zz);
        }
    }
}

// ---------------- final FC stage 1: partial dot over k-chunks ----------------
__global__ __launch_bounds__(128) void fc_partial_kernel(const bf16* __restrict__ out_pre,
                                                         const void* __restrict__ W_fc,
                                                         float* __restrict__ accbuf,
                                                         const int* __restrict__ flag) {
    const bool f = (*flag != 0);
    const int n = threadIdx.x;                   // 0..127
    const int KC = (Lz * DM) / 512;              // 1024
    const int k0 = blockIdx.x * KC;
    float acc[Bz];
    #pragma unroll
    for (int b = 0; b < Bz; ++b) acc[b] = 0.f;
    for (int k = k0; k < k0 + KC; ++k) {
        float w = ldv(W_fc, (size_t)k * OD + n, f);
        #pragma unroll
        for (int b = 0; b < Bz; ++b) acc[b] += tf(out_pre[(size_t)b * (Lz * DM) + k]) * w;
    }
    #pragma unroll
    for (int b = 0; b < Bz; ++b) atomicAdd(&accbuf[b * OD + n], acc[b]);
}

__global__ void fc_final_kernel(const float* __restrict__ accbuf,
                                const void* __restrict__ b_fc, void* __restrict__ out,
                                const int* __restrict__ flag) {
    const bool f = (*flag != 0);
    int i = blockIdx.x * 256 + threadIdx.x;
    if (i < Bz * OD) {
        float v = accbuf[i] + ldv(b_fc, i & (OD - 1), f);
        if (f) ((float*)out)[i] = v;
        else   ((bf16*)out)[i]  = __float2bfloat16(v);
    }
}

extern "C" void kernel_launch(void* const* d_in, const int* in_sizes, int n_in,
                              void* d_out, int out_size, void* d_ws, size_t ws_size,
                              hipStream_t stream) {
    const void* x       = d_in[0];
    const void* W_in    = d_in[1];
    const void* conv_w  = d_in[2];
    const void* conv_b  = d_in[3];
    const void* W_xproj = d_in[4];
    const void* W_dt    = d_in[5];
    const void* b_dt    = d_in[6];
    const void* A_log   = d_in[7];
    const void* Dp      = d_in[8];
    const void* W_out   = d_in[9];
    const void* W_fc    = d_in[10];
    const void* b_fc    = d_in[11];

    // workspace (bytes), total ~100.02 MB with aliasing:
    //  [0,32M):   xin -> dt(f16) -> outp(bf16)
    //  [32M,64M): zs=silu(z) -> y (in-place per element in scan)
    //  [64M,96M): xc
    //  [96M,100M): x_dbl fp32
    char* ws = (char*)d_ws;
    bf16*     xin   = (bf16*)(ws);
    _Float16* dt    = (_Float16*)(ws);
    bf16*     outp  = (bf16*)(ws);
    bf16*     yzs   = (bf16*)(ws + 33554432ull);
    bf16*     xc    = (bf16*)(ws + 67108864ull);
    float*    x_dbl = (float*)(ws + 100663296ull);
    float*    accb  = (float*)(ws + 104857600ull);
    int*      flag  = (int*)(ws + 104865792ull);

    dim3 blk(256);
    hipMemsetAsync(flag, 0, 4, stream);
    detect_kernel<<<256, blk, 0, stream>>>(x, flag);
    // K1a: xin = x @ W_in[:, :DI]    K1b: zs = silu(x @ W_in[:, DI:])
    hipLaunchKernelGGL((gemm_mfma<true, true, false>), dim3(DI / 128, Mrows / 128), blk, 0, stream,
                       x, DM, W_in, 2 * DI, 0, xin, DI, DM, flag);
    hipLaunchKernelGGL((gemm_mfma<true, true, true>), dim3(DI / 128, Mrows / 128), blk, 0, stream,
                       x, DM, W_in, 2 * DI, DI, yzs, DI, DM, flag);
    // K2: xc = silu(conv(xin))
    conv_silu_kernel<<<(Mrows * DI) / 256, blk, 0, stream>>>(xin, conv_w, conv_b, xc, flag);
    // K3: x_dbl = xc @ W_xproj  (16384x1024 @ 1024x64)
    hipLaunchKernelGGL((gemm64<false, true, true>), dim3(XD / 64, Mrows / 64), blk, 0, stream,
                       xc, DI, W_xproj, XD, 0, x_dbl, XD, Mrows, XD, DI, flag);
    // K4: dt = softplus(x_dbl[:,:32] @ W_dt + b_dt)  (overwrites xin region)
    dt_kernel<<<(Mrows * DI) / 256, blk, 0, stream>>>(x_dbl, W_dt, b_dt, dt, flag);
    // K5: selective scan -> y (in yzs, in-place over silu(z))
    scan_kernel<<<(Bz * DI * ST) / 256, blk, 0, stream>>>(x_dbl, dt, xc, A_log, Dp, yzs, flag);
    // K6: outp = y @ W_out  (16384x1024 @ 1024x512)
    hipLaunchKernelGGL((gemm_mfma<false, true, false>), dim3(DM / 128, Mrows / 128), blk, 0, stream,
                       yzs, DI, W_out, DM, 0, outp, DM, DI, flag);
    // K7: final FC (16 x 524288) @ (524288 x 128) + b_fc
    hipMemsetAsync(accb, 0, Bz * OD * sizeof(float), stream);
    fc_partial_kernel<<<512, dim3(128), 0, stream>>>(outp, W_fc, accb, flag);
    fc_final_kernel<<<(Bz * OD + 255) / 256, blk, 0, stream>>>(accb, b_fc, d_out, flag);
}

// Round 5
// 1538.554 us; speedup vs baseline: 2.2883x; 1.3528x over previous
//
#include <hip/hip_runtime.h>
#include <hip/hip_bf16.h>

typedef __hip_bfloat16 bf16;
typedef __bf16 bf8v __attribute__((ext_vector_type(8)));
typedef float f4v __attribute__((ext_vector_type(4)));

static __device__ __forceinline__ float tf(const bf16 v) { return __bfloat162float(v); }

// load from an input buffer whose dtype is decided at runtime (f32 flag)
static __device__ __forceinline__ float ldv(const void* p, size_t i, bool f32) {
    return f32 ? ((const float*)p)[i] : tf(((const bf16*)p)[i]);
}

// async global->LDS, 16B per lane; LDS placement = wave-uniform base + lane*16
static __device__ __forceinline__ void gld_lds16(const bf16* g, __bf16* l) {
    __builtin_amdgcn_global_load_lds(
        (const __attribute__((address_space(1))) void*)g,
        (__attribute__((address_space(3))) void*)l, 16, 0, 0);
}

constexpr int Bz = 16, Lz = 1024, DM = 512, DI = 1024, ST = 16, DC = 4, RK = 32, OD = 128;
constexpr int Mrows = Bz * Lz;           // 16384
constexpr int XD = RK + 2 * ST;          // 64 (x_dbl row)
constexpr int NC = 8, CT = Lz / NC;      // scan chunks, steps per chunk

// -------- dtype probe: sample even bf16 halves of x; f32 data -> wild values --------
__global__ void detect_kernel(const void* __restrict__ xp, int* __restrict__ flag) {
    int i = blockIdx.x * 256 + threadIdx.x;          // 0..65535
    const bf16* p = (const bf16*)xp;
    float v = tf(p[(size_t)i * 64]);                 // even idx = low half if f32
    if (!(fabsf(v) < 1e4f)) atomicAdd(flag, 1);      // NaN/inf/huge counts
}

// -------- canonicalize x to bf16 (4 elems/thread) --------
__global__ __launch_bounds__(256) void canon_kernel(const void* __restrict__ src,
                                                    bf16* __restrict__ dst,
                                                    const int* __restrict__ flag) {
    const bool f = (*flag != 0);
    size_t base = ((size_t)blockIdx.x * 256 + threadIdx.x) * 4;
    #pragma unroll
    for (int j = 0; j < 4; ++j) dst[base + j] = __float2bfloat16(ldv(src, base + j, f));
}

// -------- Wt[n][k] (bf16) = W[k][n] (runtime dtype); grid (N/32, K/32) --------
__global__ __launch_bounds__(256) void transpose_kernel(const void* __restrict__ W,
                                                        bf16* __restrict__ Wt,
                                                        int K, int N,
                                                        const int* __restrict__ flag) {
    const bool f = (*flag != 0);
    __shared__ float tile[32][33];
    int k0 = blockIdx.y * 32, n0 = blockIdx.x * 32;
    int c = threadIdx.x & 31, r4 = threadIdx.x >> 5;
    #pragma unroll
    for (int i = 0; i < 4; ++i) {
        int r = r4 + i * 8;
        tile[r][c] = ldv(W, (size_t)(k0 + r) * N + n0 + c, f);
    }
    __syncthreads();
    #pragma unroll
    for (int i = 0; i < 4; ++i) {
        int rr = r4 + i * 8;
        Wt[(size_t)(n0 + rr) * K + k0 + c] = __float2bfloat16(tile[c][rr]);
    }
}

// ============ MFMA bf16 GEMM, B^T layout, global_load_lds staging ============
// A [M][K] bf16 (lda), Bt [N][K] bf16 (ldb). Tile 128 x NT.
// SPLIT: N=2048 xz case -> cols<DI to C0, cols>=DI silu'd to C1 (both stride DI).
// CF32: write fp32 to C0.
template <int NT, bool SPLIT, bool CF32>
__global__ __launch_bounds__(256) void gemm_bt(const bf16* __restrict__ A, int lda,
                                               const bf16* __restrict__ Bt, int ldb,
                                               void* __restrict__ C0, void* __restrict__ C1,
                                               int ldc, int K) {
    constexpr int MI = (NT == 128) ? 4 : 2;
    constexpr int NI = 4;
    __shared__ __align__(16) __bf16 As[128 * 32];
    __shared__ __align__(16) __bf16 Bs[NT * 32];
    const int tid = threadIdx.x, lane = tid & 63, w = tid >> 6;
    const int l15 = lane & 15, quad = lane >> 4;
    const int wm = (NT == 128) ? (w >> 1) * 64 : w * 32;
    const int wn = (NT == 128) ? (w & 1) * 64 : 0;
    const int m0 = blockIdx.y * 128, n0 = blockIdx.x * NT;

    f4v acc[MI][NI];
    #pragma unroll
    for (int i = 0; i < MI; ++i)
        #pragma unroll
        for (int j = 0; j < NI; ++j)
            #pragma unroll
            for (int r = 0; r < 4; ++r) acc[i][j][r] = 0.f;

    const int arow = w * 32 + (lane >> 2), ach = lane & 3;
    for (int k0 = 0; k0 < K; k0 += 32) {
        // A: 128 rows x 32k, lane-linear LDS (pitch 32 shorts, no pad)
        {
            const bf16* g0 = A + (size_t)(m0 + arow) * lda + k0 + ach * 8;
            gld_lds16(g0, &As[w * 1024 + lane * 8]);
            gld_lds16(g0 + (size_t)16 * lda, &As[w * 1024 + 512 + lane * 8]);
        }
        if (NT == 128) {
            const bf16* g0 = Bt + (size_t)(n0 + arow) * ldb + k0 + ach * 8;
            gld_lds16(g0, &Bs[w * 1024 + lane * 8]);
            gld_lds16(g0 + (size_t)16 * ldb, &Bs[w * 1024 + 512 + lane * 8]);
        } else {
            const int brow = w * 16 + (lane >> 2);
            const bf16* g0 = Bt + (size_t)(n0 + brow) * ldb + k0 + ach * 8;
            gld_lds16(g0, &Bs[w * 512 + lane * 8]);
        }
        __syncthreads();
        bf8v a[MI], b[NI];
        #pragma unroll
        for (int mi = 0; mi < MI; ++mi)
            a[mi] = *(const bf8v*)&As[(wm + mi * 16 + l15) * 32 + quad * 8];
        #pragma unroll
        for (int ni = 0; ni < NI; ++ni)
            b[ni] = *(const bf8v*)&Bs[(wn + ni * 16 + l15) * 32 + quad * 8];
        #pragma unroll
        for (int mi = 0; mi < MI; ++mi)
            #pragma unroll
            for (int ni = 0; ni < NI; ++ni)
                acc[mi][ni] = __builtin_amdgcn_mfma_f32_16x16x32_bf16(a[mi], b[ni], acc[mi][ni], 0, 0, 0);
        __syncthreads();
    }
    // epilogue: D row = quad*4+r, col = lane&15
    #pragma unroll
    for (int mi = 0; mi < MI; ++mi)
        #pragma unroll
        for (int ni = 0; ni < NI; ++ni)
            #pragma unroll
            for (int r = 0; r < 4; ++r) {
                int row = m0 + wm + mi * 16 + quad * 4 + r;
                int col = n0 + wn + ni * 16 + l15;
                float v = acc[mi][ni][r];
                if (SPLIT) {
                    if (col < DI) ((bf16*)C0)[(size_t)row * DI + col] = __float2bfloat16(v);
                    else ((bf16*)C1)[(size_t)row * DI + col - DI] =
                             __float2bfloat16(v / (1.f + __expf(-v)));
                } else if (CF32) {
                    ((float*)C0)[(size_t)row * ldc + col] = v;
                } else {
                    ((bf16*)C0)[(size_t)row * ldc + col] = __float2bfloat16(v);
                }
            }
}

// ---------------- conv (depthwise, causal, DC=4) + SiLU ----------------
__global__ __launch_bounds__(256) void conv_silu_kernel(const bf16* __restrict__ xin,
                                                        const void* __restrict__ conv_w,
                                                        const void* __restrict__ conv_b,
                                                        bf16* __restrict__ xc,
                                                        const int* __restrict__ flag) {
    const bool f = (*flag != 0);
    int g = blockIdx.x * 256 + threadIdx.x;       // g = b*2^20 + t*2^10 + d
    int d = g & (DI - 1);
    int t = (g >> 10) & (Lz - 1);
    int b = g >> 20;
    const bf16* xin_b = xin + (size_t)b * Lz * DI;
    float acc = ldv(conv_b, d, f);
    #pragma unroll
    for (int j = 0; j < DC; ++j) {
        int tt = t + j - (DC - 1);
        if (tt >= 0) acc += tf(xin_b[(size_t)tt * DI + d]) * ldv(conv_w, d * DC + j, f);
    }
    xc[(size_t)g] = __float2bfloat16(acc / (1.f + __expf(-acc)));
}

// ------------- dt[m,d] = softplus(x_dbl[m,:32] @ W_dt[:,d] + b_dt[d]) -------------
__global__ __launch_bounds__(256) void dt_kernel(const float* __restrict__ x_dbl,
                                                 const void* __restrict__ W_dt,
                                                 const void* __restrict__ b_dt,
                                                 _Float16* __restrict__ dt,
                                                 const int* __restrict__ flag) {
    const bool f = (*flag != 0);
    int g = blockIdx.x * 256 + threadIdx.x;       // g = m*1024 + d
    int d = g & (DI - 1);
    int m = g >> 10;
    float acc = ldv(b_dt, d, f);
    const float* xr = x_dbl + (size_t)m * XD;
    #pragma unroll
    for (int k = 0; k < RK; ++k) acc += xr[k] * ldv(W_dt, (size_t)k * DI + d, f);
    float dtv = (acc > 15.f) ? acc : __logf(1.f + __expf(acc));
    dt[(size_t)g] = (_Float16)dtv;
}

// ======== chunked selective scan: gg = ((b*DI+d)*NC + c), 16 lanes per group ========
__global__ __launch_bounds__(256) void scan_pass1(const float* __restrict__ x_dbl,
                                                  const _Float16* __restrict__ dt,
                                                  const bf16* __restrict__ xc,
                                                  const void* __restrict__ A_log,
                                                  float* __restrict__ hbuf,
                                                  float* __restrict__ dtsum,
                                                  const int* __restrict__ flag) {
    const bool f = (*flag != 0);
    int tid = threadIdx.x, s = tid & 15;
    int gg = blockIdx.x * 16 + (tid >> 4);
    int c = gg & (NC - 1), d = (gg >> 3) & (DI - 1), b = gg >> 13;
    float A_s = -__expf(ldv(A_log, d * ST + s, f));
    const float*    xd   = x_dbl + ((size_t)b * Lz + c * CT) * XD;
    const _Float16* dt_b = dt + ((size_t)b * Lz + c * CT) * DI + d;
    const bf16*     xc_b = xc + ((size_t)b * Lz + c * CT) * DI + d;
    float h = 0.f, S = 0.f;
    #pragma unroll 4
    for (int t = 0; t < CT; ++t) {
        float dtv = (float)dt_b[(size_t)t * DI];
        float u   = tf(xc_b[(size_t)t * DI]);
        float Bv  = xd[(size_t)t * XD + RK + s];
        h = h * __expf(dtv * A_s) + dtv * u * Bv;
        S += dtv;
    }
    hbuf[(size_t)gg * 16 + s] = h;
    if (s == 0) dtsum[gg] = S;
}

__global__ __launch_bounds__(256) void scan_prefix(float* __restrict__ hbuf,
                                                   const float* __restrict__ dtsum,
                                                   const void* __restrict__ A_log,
                                                   const int* __restrict__ flag) {
    const bool f = (*flag != 0);
    int tid = threadIdx.x, s = tid & 15;
    int g2 = blockIdx.x * 16 + (tid >> 4);        // b*DI + d
    int d = g2 & (DI - 1);
    float A_s = -__expf(ldv(A_log, d * ST + s, f));
    float hrun = 0.f;
    #pragma unroll
    for (int c = 0; c < NC; ++c) {
        size_t idx = ((size_t)g2 * NC + c) * 16 + s;
        float he = hbuf[idx];
        float P = __expf(A_s * dtsum[g2 * NC + c]);
        hbuf[idx] = hrun;                          // h_in for chunk c
        hrun = hrun * P + he;
    }
}

__global__ __launch_bounds__(256) void scan_pass2(const float* __restrict__ x_dbl,
                                                  const _Float16* __restrict__ dt,
                                                  const bf16* __restrict__ xc,
                                                  const void* __restrict__ A_log,
                                                  const void* __restrict__ Dp,
                                                  bf16* __restrict__ yzs,   // in: silu(z), out: y
                                                  const float* __restrict__ hbuf,
                                                  const int* __restrict__ flag) {
    const bool f = (*flag != 0);
    int tid = threadIdx.x, s = tid & 15;
    int gg = blockIdx.x * 16 + (tid >> 4);
    int c = gg & (NC - 1), d = (gg >> 3) & (DI - 1), b = gg >> 13;
    float A_s = -__expf(ldv(A_log, d * ST + s, f));
    float Dp_d = ldv(Dp, d, f);
    float h = hbuf[(size_t)gg * 16 + s];
    const float*    xd   = x_dbl + ((size_t)b * Lz + c * CT) * XD;
    const _Float16* dt_b = dt + ((size_t)b * Lz + c * CT) * DI + d;
    const bf16*     xc_b = xc + ((size_t)b * Lz + c * CT) * DI + d;
    bf16*           yz_b = yzs + ((size_t)b * Lz + c * CT) * DI + d;
    #pragma unroll 2
    for (int t = 0; t < CT; ++t) {
        const float* xr = xd + (size_t)t * XD;
        float dtv = (float)dt_b[(size_t)t * DI];
        float u   = tf(xc_b[(size_t)t * DI]);
        float Bv  = xr[RK + s];
        float Cv  = xr[RK + ST + s];
        h = h * __expf(dtv * A_s) + dtv * u * Bv;
        float p = h * Cv;
        p += __shfl_xor(p, 1, 16);
        p += __shfl_xor(p, 2, 16);
        p += __shfl_xor(p, 4, 16);
        p += __shfl_xor(p, 8, 16);
        if (s == 0) {
            float zz = tf(yz_b[(size_t)t * DI]);
            yz_b[(size_t)t * DI] = __float2bfloat16((p + Dp_d * u) * zz);
        }
    }
}

// ---------------- final FC ----------------
__global__ __launch_bounds__(128) void fc_partial_kernel(const bf16* __restrict__ out_pre,
                                                         const void* __restrict__ W_fc,
                                                         float* __restrict__ accbuf,
                                                         const int* __restrict__ flag) {
    const bool f = (*flag != 0);
    const int n = threadIdx.x;                   // 0..127
    const int KC = 256;
    const int k0 = blockIdx.x * KC;
    float acc[Bz];
    #pragma unroll
    for (int b = 0; b < Bz; ++b) acc[b] = 0.f;
    for (int k = k0; k < k0 + KC; ++k) {
        float w = ldv(W_fc, (size_t)k * OD + n, f);
        #pragma unroll
        for (int b = 0; b < Bz; ++b) acc[b] += tf(out_pre[(size_t)b * (Lz * DM) + k]) * w;
    }
    #pragma unroll
    for (int b = 0; b < Bz; ++b) atomicAdd(&accbuf[b * OD + n], acc[b]);
}

__global__ void fc_final_kernel(const float* __restrict__ accbuf,
                                const void* __restrict__ b_fc, void* __restrict__ out,
                                const int* __restrict__ flag) {
    const bool f = (*flag != 0);
    int i = blockIdx.x * 256 + threadIdx.x;
    if (i < Bz * OD) {
        float v = accbuf[i] + ldv(b_fc, i & (OD - 1), f);
        if (f) ((float*)out)[i] = v;
        else   ((bf16*)out)[i]  = __float2bfloat16(v);
    }
}

extern "C" void kernel_launch(void* const* d_in, const int* in_sizes, int n_in,
                              void* d_out, int out_size, void* d_ws, size_t ws_size,
                              hipStream_t stream) {
    const void* x       = d_in[0];
    const void* W_in    = d_in[1];
    const void* conv_w  = d_in[2];
    const void* conv_b  = d_in[3];
    const void* W_xproj = d_in[4];
    const void* W_dt    = d_in[5];
    const void* b_dt    = d_in[6];
    const void* A_log   = d_in[7];
    const void* Dp      = d_in[8];
    const void* W_out   = d_in[9];
    const void* W_fc    = d_in[10];
    const void* b_fc    = d_in[11];

    // workspace layout (bytes), total ~134 MB:
    char* ws = (char*)d_ws;
    bf16*     xin    = (bf16*)(ws);                      // [0,32M) ; dt(f16) aliases after conv
    _Float16* dt     = (_Float16*)(ws);
    bf16*     yzs    = (bf16*)(ws + 33554432ull);        // [32M,64M) silu(z) -> y
    bf16*     xc     = (bf16*)(ws + 67108864ull);        // [64M,96M)
    float*    x_dbl  = (float*)(ws + 100663296ull);      // [96M,100M) fp32
    bf16*     xb     = (bf16*)(ws + 104857600ull);       // [100M,116M) canonical x; outp aliases
    bf16*     outp   = (bf16*)(ws + 104857600ull);
    float*    hbuf   = (float*)(ws + 121634816ull);      // 8 MB
    float*    dtsum  = (float*)(ws + 130023424ull);      // 512 KB
    bf16*     Wt_in  = (bf16*)(ws + 130547712ull);       // 2 MB  [2048][512]
    bf16*     Wt_out = (bf16*)(ws + 132644864ull);       // 1 MB  [512][1024]
    bf16*     Wt_xp  = (bf16*)(ws + 133693440ull);       // 128KB [64][1024]
    float*    accb   = (float*)(ws + 133824512ull);
    int*      flag   = (int*)(ws + 133832704ull);

    dim3 blk(256);
    hipMemsetAsync(flag, 0, 4, stream);
    detect_kernel<<<256, blk, 0, stream>>>(x, flag);
    // canonicalize / transpose to bf16 B^T
    canon_kernel<<<(Mrows * DM) / 1024, blk, 0, stream>>>(x, xb, flag);
    transpose_kernel<<<dim3(2 * DI / 32, DM / 32), blk, 0, stream>>>(W_in, Wt_in, DM, 2 * DI, flag);
    transpose_kernel<<<dim3(DM / 32, DI / 32), blk, 0, stream>>>(W_out, Wt_out, DI, DM, flag);
    transpose_kernel<<<dim3(XD / 32, DI / 32), blk, 0, stream>>>(W_xproj, Wt_xp, DI, XD, flag);
    // K1: [xin | silu(z)] = x @ W_in  (single fused GEMM, split epilogue)
    hipLaunchKernelGGL((gemm_bt<128, true, false>), dim3(2 * DI / 128, Mrows / 128), blk, 0, stream,
                       xb, DM, Wt_in, DM, xin, yzs, DI, DM);
    // K2: xc = silu(conv(xin))
    conv_silu_kernel<<<(Mrows * DI) / 256, blk, 0, stream>>>(xin, conv_w, conv_b, xc, flag);
    // K3: x_dbl = xc @ W_xproj (fp32 out)
    hipLaunchKernelGGL((gemm_bt<64, false, true>), dim3(1, Mrows / 128), blk, 0, stream,
                       xc, DI, Wt_xp, DI, x_dbl, (void*)0, XD, DI);
    // K4: dt (overwrites xin region)
    dt_kernel<<<(Mrows * DI) / 256, blk, 0, stream>>>(x_dbl, W_dt, b_dt, dt, flag);
    // K5: chunked scan
    scan_pass1<<<(Bz * DI * NC) / 16, blk, 0, stream>>>(x_dbl, dt, xc, A_log, hbuf, dtsum, flag);
    scan_prefix<<<(Bz * DI) / 16, blk, 0, stream>>>(hbuf, dtsum, A_log, flag);
    scan_pass2<<<(Bz * DI * NC) / 16, blk, 0, stream>>>(x_dbl, dt, xc, A_log, Dp, yzs, hbuf, flag);
    // K6: outp = y @ W_out
    hipLaunchKernelGGL((gemm_bt<128, false, false>), dim3(DM / 128, Mrows / 128), blk, 0, stream,
                       yzs, DI, Wt_out, DI, outp, (void*)0, DM, DI);
    // K7: final FC
    hipMemsetAsync(accb, 0, Bz * OD * sizeof(float), stream);
    fc_partial_kernel<<<2048, dim3(128), 0, stream>>>(outp, W_fc, accb, flag);
    fc_final_kernel<<<(Bz * OD + 255) / 256, blk, 0, stream>>>(accb, b_fc, d_out, flag);
}

// Round 6
// 1081.588 us; speedup vs baseline: 3.2551x; 1.4225x over previous
//
#include <hip/hip_runtime.h>
#include <hip/hip_bf16.h>

typedef __hip_bfloat16 bf16;
typedef __bf16 bf8v __attribute__((ext_vector_type(8)));
typedef float f4v __attribute__((ext_vector_type(4)));

static __device__ __forceinline__ float tf(const bf16 v) { return __bfloat162float(v); }

// load from an input buffer whose dtype is decided at runtime (f32 flag)
static __device__ __forceinline__ float ldv(const void* p, size_t i, bool f32) {
    return f32 ? ((const float*)p)[i] : tf(((const bf16*)p)[i]);
}

// async global->LDS, 16B per lane; LDS placement = wave-uniform base + lane*16
static __device__ __forceinline__ void gld_lds16(const bf16* g, __bf16* l) {
    __builtin_amdgcn_global_load_lds(
        (const __attribute__((address_space(1))) void*)g,
        (__attribute__((address_space(3))) void*)l, 16, 0, 0);
}

constexpr int Bz = 16, Lz = 1024, DM = 512, DI = 1024, ST = 16, DC = 4, RK = 32, OD = 128;
constexpr int Mrows = Bz * Lz;           // 16384
constexpr int XD = RK + 2 * ST;          // 64 (x_dbl row)
constexpr int NC = 8, CT = Lz / NC;      // scan chunks, steps per chunk

// -------- dtype probe: sample even bf16 halves of x; f32 data -> wild values --------
__global__ void detect_kernel(const void* __restrict__ xp, int* __restrict__ flag) {
    int i = blockIdx.x * 256 + threadIdx.x;          // 0..65535
    const bf16* p = (const bf16*)xp;
    float v = tf(p[(size_t)i * 64]);                 // even idx = low half if f32
    if (!(fabsf(v) < 1e4f)) atomicAdd(flag, 1);      // NaN/inf/huge counts
}

// -------- canonicalize x to bf16 (4 elems/thread) --------
__global__ __launch_bounds__(256) void canon_kernel(const void* __restrict__ src,
                                                    bf16* __restrict__ dst,
                                                    const int* __restrict__ flag) {
    const bool f = (*flag != 0);
    size_t base = ((size_t)blockIdx.x * 256 + threadIdx.x) * 4;
    #pragma unroll
    for (int j = 0; j < 4; ++j) dst[base + j] = __float2bfloat16(ldv(src, base + j, f));
}

// -------- Wt[n][k] (bf16) = W[k][n] (runtime dtype); grid (N/32, K/32) --------
__global__ __launch_bounds__(256) void transpose_kernel(const void* __restrict__ W,
                                                        bf16* __restrict__ Wt,
                                                        int K, int N,
                                                        const int* __restrict__ flag) {
    const bool f = (*flag != 0);
    __shared__ float tile[32][33];
    int k0 = blockIdx.y * 32, n0 = blockIdx.x * 32;
    int c = threadIdx.x & 31, r4 = threadIdx.x >> 5;
    #pragma unroll
    for (int i = 0; i < 4; ++i) {
        int r = r4 + i * 8;
        tile[r][c] = ldv(W, (size_t)(k0 + r) * N + n0 + c, f);
    }
    __syncthreads();
    #pragma unroll
    for (int i = 0; i < 4; ++i) {
        int rr = r4 + i * 8;
        Wt[(size_t)(n0 + rr) * K + k0 + c] = __float2bfloat16(tile[c][rr]);
    }
}

// ============ MFMA bf16 GEMM, B^T layout, global_load_lds staging ============
template <int NT, bool SPLIT, bool CF32>
__global__ __launch_bounds__(256) void gemm_bt(const bf16* __restrict__ A, int lda,
                                               const bf16* __restrict__ Bt, int ldb,
                                               void* __restrict__ C0, void* __restrict__ C1,
                                               int ldc, int K) {
    constexpr int MI = (NT == 128) ? 4 : 2;
    constexpr int NI = 4;
    __shared__ __align__(16) __bf16 As[128 * 32];
    __shared__ __align__(16) __bf16 Bs[NT * 32];
    const int tid = threadIdx.x, lane = tid & 63, w = tid >> 6;
    const int l15 = lane & 15, quad = lane >> 4;
    const int wm = (NT == 128) ? (w >> 1) * 64 : w * 32;
    const int wn = (NT == 128) ? (w & 1) * 64 : 0;
    const int m0 = blockIdx.y * 128, n0 = blockIdx.x * NT;

    f4v acc[MI][NI];
    #pragma unroll
    for (int i = 0; i < MI; ++i)
        #pragma unroll
        for (int j = 0; j < NI; ++j)
            #pragma unroll
            for (int r = 0; r < 4; ++r) acc[i][j][r] = 0.f;

    const int arow = w * 32 + (lane >> 2), ach = lane & 3;
    for (int k0 = 0; k0 < K; k0 += 32) {
        {
            const bf16* g0 = A + (size_t)(m0 + arow) * lda + k0 + ach * 8;
            gld_lds16(g0, &As[w * 1024 + lane * 8]);
            gld_lds16(g0 + (size_t)16 * lda, &As[w * 1024 + 512 + lane * 8]);
        }
        if (NT == 128) {
            const bf16* g0 = Bt + (size_t)(n0 + arow) * ldb + k0 + ach * 8;
            gld_lds16(g0, &Bs[w * 1024 + lane * 8]);
            gld_lds16(g0 + (size_t)16 * ldb, &Bs[w * 1024 + 512 + lane * 8]);
        } else {
            const int brow = w * 16 + (lane >> 2);
            const bf16* g0 = Bt + (size_t)(n0 + brow) * ldb + k0 + ach * 8;
            gld_lds16(g0, &Bs[w * 512 + lane * 8]);
        }
        __syncthreads();
        bf8v a[MI], b[NI];
        #pragma unroll
        for (int mi = 0; mi < MI; ++mi)
            a[mi] = *(const bf8v*)&As[(wm + mi * 16 + l15) * 32 + quad * 8];
        #pragma unroll
        for (int ni = 0; ni < NI; ++ni)
            b[ni] = *(const bf8v*)&Bs[(wn + ni * 16 + l15) * 32 + quad * 8];
        #pragma unroll
        for (int mi = 0; mi < MI; ++mi)
            #pragma unroll
            for (int ni = 0; ni < NI; ++ni)
                acc[mi][ni] = __builtin_amdgcn_mfma_f32_16x16x32_bf16(a[mi], b[ni], acc[mi][ni], 0, 0, 0);
        __syncthreads();
    }
    #pragma unroll
    for (int mi = 0; mi < MI; ++mi)
        #pragma unroll
        for (int ni = 0; ni < NI; ++ni)
            #pragma unroll
            for (int r = 0; r < 4; ++r) {
                int row = m0 + wm + mi * 16 + quad * 4 + r;
                int col = n0 + wn + ni * 16 + l15;
                float v = acc[mi][ni][r];
                if (SPLIT) {
                    if (col < DI) ((bf16*)C0)[(size_t)row * DI + col] = __float2bfloat16(v);
                    else ((bf16*)C1)[(size_t)row * DI + col - DI] =
                             __float2bfloat16(v / (1.f + __expf(-v)));
                } else if (CF32) {
                    ((float*)C0)[(size_t)row * ldc + col] = v;
                } else {
                    ((bf16*)C0)[(size_t)row * ldc + col] = __float2bfloat16(v);
                }
            }
}

// ---------------- conv (depthwise, causal, DC=4) + SiLU ----------------
__global__ __launch_bounds__(256) void conv_silu_kernel(const bf16* __restrict__ xin,
                                                        const void* __restrict__ conv_w,
                                                        const void* __restrict__ conv_b,
                                                        bf16* __restrict__ xc,
                                                        const int* __restrict__ flag) {
    const bool f = (*flag != 0);
    int g = blockIdx.x * 256 + threadIdx.x;       // g = b*2^20 + t*2^10 + d
    int d = g & (DI - 1);
    int t = (g >> 10) & (Lz - 1);
    int b = g >> 20;
    const bf16* xin_b = xin + (size_t)b * Lz * DI;
    float acc = ldv(conv_b, d, f);
    #pragma unroll
    for (int j = 0; j < DC; ++j) {
        int tt = t + j - (DC - 1);
        if (tt >= 0) acc += tf(xin_b[(size_t)tt * DI + d]) * ldv(conv_w, d * DC + j, f);
    }
    xc[(size_t)g] = __float2bfloat16(acc / (1.f + __expf(-acc)));
}

// ------------- dt[m,d] = softplus(x_dbl[m,:32] @ W_dt[:,d] + b_dt[d]) -------------
__global__ __launch_bounds__(256) void dt_kernel(const float* __restrict__ x_dbl,
                                                 const void* __restrict__ W_dt,
                                                 const void* __restrict__ b_dt,
                                                 _Float16* __restrict__ dt,
                                                 const int* __restrict__ flag) {
    const bool f = (*flag != 0);
    int g = blockIdx.x * 256 + threadIdx.x;       // g = m*1024 + d
    int d = g & (DI - 1);
    int m = g >> 10;
    float acc = ldv(b_dt, d, f);
    const float* xr = x_dbl + (size_t)m * XD;
    #pragma unroll
    for (int k = 0; k < RK; ++k) acc += xr[k] * ldv(W_dt, (size_t)k * DI + d, f);
    float dtv = (acc > 15.f) ? acc : __logf(1.f + __expf(acc));
    dt[(size_t)g] = (_Float16)dtv;
}

// ======== chunked selective scan, d-parallel lanes: 16 h-states per lane ========
// grid (NC, DI/256, Bz) x 256 thr. All global streams coalesced along d.
__global__ __launch_bounds__(256) void scan_pass1(const float* __restrict__ x_dbl,
                                                  const _Float16* __restrict__ dt,
                                                  const bf16* __restrict__ xc,
                                                  const void* __restrict__ A_log,
                                                  float* __restrict__ hbuf,
                                                  float* __restrict__ dtsum,
                                                  const int* __restrict__ flag) {
    const bool f = (*flag != 0);
    const int c = blockIdx.x, b = blockIdx.z;
    const int d = blockIdx.y * 256 + threadIdx.x;
    __shared__ float Brow[CT][16];
    #pragma unroll
    for (int i = 0; i < 2; ++i) {                 // 2048 f32, 2 float4/thread
        int idx = threadIdx.x + i * 256;
        int r = idx >> 2, q = idx & 3;
        *(f4v*)&Brow[r][q * 4] =
            *(const f4v*)(x_dbl + ((size_t)(b * Lz + c * CT + r)) * XD + RK + q * 4);
    }
    __syncthreads();
    float A[ST];
    #pragma unroll
    for (int s = 0; s < ST; ++s) A[s] = -__expf(ldv(A_log, (size_t)d * ST + s, f));
    float h[ST] = {};
    float S = 0.f;
    const _Float16* dtp = dt + (size_t)(b * Lz + c * CT) * DI + d;
    const bf16*     xcp = xc + (size_t)(b * Lz + c * CT) * DI + d;
    for (int t = 0; t < CT; ++t) {
        float dtv = (float)dtp[(size_t)t * DI];
        float du  = dtv * tf(xcp[(size_t)t * DI]);
        S += dtv;
        #pragma unroll
        for (int s = 0; s < ST; ++s)
            h[s] = h[s] * __expf(dtv * A[s]) + du * Brow[t][s];
    }
    float* hp = hbuf + ((size_t)(b * DI + d) * NC + c) * 16;
    #pragma unroll
    for (int s = 0; s < ST; ++s) hp[s] = h[s];
    dtsum[(size_t)(b * DI + d) * NC + c] = S;
}

__global__ __launch_bounds__(256) void scan_prefix(float* __restrict__ hbuf,
                                                   const float* __restrict__ dtsum,
                                                   const void* __restrict__ A_log,
                                                   const int* __restrict__ flag) {
    const bool f = (*flag != 0);
    int g2 = blockIdx.x * 256 + threadIdx.x;      // b*DI + d
    int d = g2 & (DI - 1);
    float A[ST];
    #pragma unroll
    for (int s = 0; s < ST; ++s) A[s] = -__expf(ldv(A_log, (size_t)d * ST + s, f));
    float hrun[ST] = {};
    for (int c = 0; c < NC; ++c) {
        float* hp = hbuf + ((size_t)g2 * NC + c) * 16;
        float S = dtsum[(size_t)g2 * NC + c];
        #pragma unroll
        for (int s = 0; s < ST; ++s) {
            float he = hp[s];
            float P = __expf(A[s] * S);
            hp[s] = hrun[s];                       // h_in for chunk c
            hrun[s] = hrun[s] * P + he;
        }
    }
}

__global__ __launch_bounds__(256) void scan_pass2(const float* __restrict__ x_dbl,
                                                  const _Float16* __restrict__ dt,
                                                  const bf16* __restrict__ xc,
                                                  const void* __restrict__ A_log,
                                                  const void* __restrict__ Dp,
                                                  bf16* __restrict__ yzs,   // in: silu(z), out: y
                                                  const float* __restrict__ hbuf,
                                                  const int* __restrict__ flag) {
    const bool f = (*flag != 0);
    const int c = blockIdx.x, b = blockIdx.z;
    const int d = blockIdx.y * 256 + threadIdx.x;
    __shared__ float BC[CT][32];                  // [t][0:16)=B, [16:32)=C
    #pragma unroll
    for (int i = 0; i < 4; ++i) {                 // 4096 f32, 4 float4/thread
        int idx = threadIdx.x + i * 256;
        int r = idx >> 3, q = idx & 7;
        *(f4v*)&BC[r][q * 4] =
            *(const f4v*)(x_dbl + ((size_t)(b * Lz + c * CT + r)) * XD + RK + q * 4);
    }
    __syncthreads();
    float A[ST];
    #pragma unroll
    for (int s = 0; s < ST; ++s) A[s] = -__expf(ldv(A_log, (size_t)d * ST + s, f));
    float Dp_d = ldv(Dp, d, f);
    float h[ST];
    const float* hp = hbuf + ((size_t)(b * DI + d) * NC + c) * 16;
    #pragma unroll
    for (int s = 0; s < ST; ++s) h[s] = hp[s];
    const _Float16* dtp = dt + (size_t)(b * Lz + c * CT) * DI + d;
    const bf16*     xcp = xc + (size_t)(b * Lz + c * CT) * DI + d;
    bf16*           yzp = yzs + (size_t)(b * Lz + c * CT) * DI + d;
    for (int t = 0; t < CT; ++t) {
        float dtv = (float)dtp[(size_t)t * DI];
        float u   = tf(xcp[(size_t)t * DI]);
        float du  = dtv * u;
        float p = 0.f;
        #pragma unroll
        for (int s = 0; s < ST; ++s) {
            h[s] = h[s] * __expf(dtv * A[s]) + du * BC[t][s];
            p += h[s] * BC[t][16 + s];
        }
        float zz = tf(yzp[(size_t)t * DI]);
        yzp[(size_t)t * DI] = __float2bfloat16((p + Dp_d * u) * zz);
    }
}

// ---------------- final FC ----------------
__global__ __launch_bounds__(128) void fc_partial_kernel(const bf16* __restrict__ out_pre,
                                                         const void* __restrict__ W_fc,
                                                         float* __restrict__ accbuf,
                                                         const int* __restrict__ flag) {
    const bool f = (*flag != 0);
    const int n = threadIdx.x;                   // 0..127
    const int KC = 256;
    const int k0 = blockIdx.x * KC;
    float acc[Bz];
    #pragma unroll
    for (int b = 0; b < Bz; ++b) acc[b] = 0.f;
    for (int k = k0; k < k0 + KC; ++k) {
        float w = ldv(W_fc, (size_t)k * OD + n, f);
        #pragma unroll
        for (int b = 0; b < Bz; ++b) acc[b] += tf(out_pre[(size_t)b * (Lz * DM) + k]) * w;
    }
    #pragma unroll
    for (int b = 0; b < Bz; ++b) atomicAdd(&accbuf[b * OD + n], acc[b]);
}

__global__ void fc_final_kernel(const float* __restrict__ accbuf,
                                const void* __restrict__ b_fc, void* __restrict__ out,
                                const int* __restrict__ flag) {
    const bool f = (*flag != 0);
    int i = blockIdx.x * 256 + threadIdx.x;
    if (i < Bz * OD) {
        float v = accbuf[i] + ldv(b_fc, i & (OD - 1), f);
        if (f) ((float*)out)[i] = v;
        else   ((bf16*)out)[i]  = __float2bfloat16(v);
    }
}

extern "C" void kernel_launch(void* const* d_in, const int* in_sizes, int n_in,
                              void* d_out, int out_size, void* d_ws, size_t ws_size,
                              hipStream_t stream) {
    const void* x       = d_in[0];
    const void* W_in    = d_in[1];
    const void* conv_w  = d_in[2];
    const void* conv_b  = d_in[3];
    const void* W_xproj = d_in[4];
    const void* W_dt    = d_in[5];
    const void* b_dt    = d_in[6];
    const void* A_log   = d_in[7];
    const void* Dp      = d_in[8];
    const void* W_out   = d_in[9];
    const void* W_fc    = d_in[10];
    const void* b_fc    = d_in[11];

    // workspace layout (bytes), total ~134 MB:
    char* ws = (char*)d_ws;
    bf16*     xin    = (bf16*)(ws);                      // [0,32M) ; dt(f16) aliases after conv
    _Float16* dt     = (_Float16*)(ws);
    bf16*     yzs    = (bf16*)(ws + 33554432ull);        // [32M,64M) silu(z) -> y
    bf16*     xc     = (bf16*)(ws + 67108864ull);        // [64M,96M)
    float*    x_dbl  = (float*)(ws + 100663296ull);      // [96M,100M) fp32
    bf16*     xb     = (bf16*)(ws + 104857600ull);       // [100M,116M) canonical x; outp aliases
    bf16*     outp   = (bf16*)(ws + 104857600ull);
    float*    hbuf   = (float*)(ws + 121634816ull);      // 8 MB
    float*    dtsum  = (float*)(ws + 130023424ull);      // 512 KB
    bf16*     Wt_in  = (bf16*)(ws + 130547712ull);       // 2 MB  [2048][512]
    bf16*     Wt_out = (bf16*)(ws + 132644864ull);       // 1 MB  [512][1024]
    bf16*     Wt_xp  = (bf16*)(ws + 133693440ull);       // 128KB [64][1024]
    float*    accb   = (float*)(ws + 133824512ull);
    int*      flag   = (int*)(ws + 133832704ull);

    dim3 blk(256);
    hipMemsetAsync(flag, 0, 4, stream);
    detect_kernel<<<256, blk, 0, stream>>>(x, flag);
    // canonicalize / transpose to bf16 B^T
    canon_kernel<<<(Mrows * DM) / 1024, blk, 0, stream>>>(x, xb, flag);
    transpose_kernel<<<dim3(2 * DI / 32, DM / 32), blk, 0, stream>>>(W_in, Wt_in, DM, 2 * DI, flag);
    transpose_kernel<<<dim3(DM / 32, DI / 32), blk, 0, stream>>>(W_out, Wt_out, DI, DM, flag);
    transpose_kernel<<<dim3(XD / 32, DI / 32), blk, 0, stream>>>(W_xproj, Wt_xp, DI, XD, flag);
    // K1: [xin | silu(z)] = x @ W_in  (single fused GEMM, split epilogue)
    hipLaunchKernelGGL((gemm_bt<128, true, false>), dim3(2 * DI / 128, Mrows / 128), blk, 0, stream,
                       xb, DM, Wt_in, DM, xin, yzs, DI, DM);
    // K2: xc = silu(conv(xin))
    conv_silu_kernel<<<(Mrows * DI) / 256, blk, 0, stream>>>(xin, conv_w, conv_b, xc, flag);
    // K3: x_dbl = xc @ W_xproj (fp32 out)
    hipLaunchKernelGGL((gemm_bt<64, false, true>), dim3(1, Mrows / 128), blk, 0, stream,
                       xc, DI, Wt_xp, DI, x_dbl, (void*)0, XD, DI);
    // K4: dt (overwrites xin region)
    dt_kernel<<<(Mrows * DI) / 256, blk, 0, stream>>>(x_dbl, W_dt, b_dt, dt, flag);
    // K5: chunked scan, d-parallel lanes
    scan_pass1<<<dim3(NC, DI / 256, Bz), blk, 0, stream>>>(x_dbl, dt, xc, A_log, hbuf, dtsum, flag);
    scan_prefix<<<(Bz * DI) / 256, blk, 0, stream>>>(hbuf, dtsum, A_log, flag);
    scan_pass2<<<dim3(NC, DI / 256, Bz), blk, 0, stream>>>(x_dbl, dt, xc, A_log, Dp, yzs, hbuf, flag);
    // K6: outp = y @ W_out
    hipLaunchKernelGGL((gemm_bt<128, false, false>), dim3(DM / 128, Mrows / 128), blk, 0, stream,
                       yzs, DI, Wt_out, DI, outp, (void*)0, DM, DI);
    // K7: final FC
    hipMemsetAsync(accb, 0, Bz * OD * sizeof(float), stream);
    fc_partial_kernel<<<2048, dim3(128), 0, stream>>>(outp, W_fc, accb, flag);
    fc_final_kernel<<<(Bz * OD + 255) / 256, blk, 0, stream>>>(accb, b_fc, d_out, flag);
}